// Round 2
// baseline (6128.293 us; speedup 1.0000x reference)
//
#include <hip/hip_runtime.h>

#define DF 128

constexpr unsigned ENC_NEGINF = 0x007FFFFFu;  // enc(-inf)

__device__ __forceinline__ unsigned enc_f(float f) {
  unsigned u = __float_as_uint(f);
  return (u & 0x80000000u) ? ~u : (u | 0x80000000u);
}
__device__ __forceinline__ float dec_f(unsigned k) {
  unsigned u = (k & 0x80000000u) ? (k & 0x7FFFFFFFu) : ~k;
  return __uint_as_float(u);
}
__device__ __forceinline__ float sigm(float x) { return 1.f / (1.f + __expf(-x)); }
__device__ __forceinline__ unsigned short f2bf(float f) {  // RNE f32->bf16
  unsigned u = __float_as_uint(f);
  u += 0x7FFFu + ((u >> 16) & 1u);
  return (unsigned short)(u >> 16);
}
__device__ __forceinline__ float bf2f(unsigned short u) {
  return __uint_as_float(((unsigned)u) << 16);
}
__device__ __forceinline__ unsigned pack2bf(float lo, float hi) {
  return (unsigned)f2bf(lo) | ((unsigned)f2bf(hi) << 16);
}

// ---------------- generic fill ----------------
__global__ void k_fill_u32(unsigned* __restrict__ p, unsigned v, long long n) {
  long long i = (long long)blockIdx.x * blockDim.x + threadIdx.x;
  long long st = (long long)gridDim.x * blockDim.x;
  for (; i < n; i += st) p[i] = v;
}

// ---------------- embeddings ----------------
__global__ __launch_bounds__(128) void k_node_embed(
    const float* __restrict__ hin, const float* __restrict__ w,
    const float* __restrict__ b, float* __restrict__ h0, int rows) {
  __shared__ float Wt[64 * DF];
  __shared__ float ar[4][64];
  int tid = threadIdx.x;
  for (int i = tid; i < 64 * DF; i += 128) Wt[(i & 63) * DF + (i >> 6)] = w[i];
  float bb = b[tid];
  __syncthreads();
  for (int r0 = blockIdx.x * 4; r0 < rows; r0 += gridDim.x * 4) {
    for (int i = tid; i < 256; i += 128) ar[i >> 6][i & 63] = hin[(size_t)r0 * 64 + i];
    __syncthreads();
    float a0 = bb, a1 = bb, a2 = bb, a3 = bb;
#pragma unroll 8
    for (int k = 0; k < 64; ++k) {
      float wv = Wt[k * DF + tid];
      a0 = fmaf(ar[0][k], wv, a0); a1 = fmaf(ar[1][k], wv, a1);
      a2 = fmaf(ar[2][k], wv, a2); a3 = fmaf(ar[3][k], wv, a3);
    }
    h0[(size_t)r0 * DF + tid] = a0;
    h0[(size_t)(r0 + 1) * DF + tid] = a1;
    h0[(size_t)(r0 + 2) * DF + tid] = a2;
    h0[(size_t)(r0 + 3) * DF + tid] = a3;
    __syncthreads();
  }
}

__global__ __launch_bounds__(128) void k_edge_embed(
    const float* __restrict__ ein, const float* __restrict__ w,
    const float* __restrict__ b, unsigned short* __restrict__ e0u, int rows) {
  __shared__ float Wt[16 * DF];
  __shared__ float ar[4][16];
  int tid = threadIdx.x;
  for (int i = tid; i < 16 * DF; i += 128) Wt[(i & 15) * DF + (i >> 4)] = w[i];
  float bb = b[tid];
  __syncthreads();
  for (int r0 = blockIdx.x * 4; r0 < rows; r0 += gridDim.x * 4) {
    if (tid < 64) ar[tid >> 4][tid & 15] = ein[(size_t)r0 * 16 + tid];
    __syncthreads();
    float a0 = bb, a1 = bb, a2 = bb, a3 = bb;
#pragma unroll
    for (int k = 0; k < 16; ++k) {
      float wv = Wt[k * DF + tid];
      a0 = fmaf(ar[0][k], wv, a0); a1 = fmaf(ar[1][k], wv, a1);
      a2 = fmaf(ar[2][k], wv, a2); a3 = fmaf(ar[3][k], wv, a3);
    }
    e0u[(size_t)r0 * DF + tid] = f2bf(a0);
    e0u[(size_t)(r0 + 1) * DF + tid] = f2bf(a1);
    e0u[(size_t)(r0 + 2) * DF + tid] = f2bf(a2);
    e0u[(size_t)(r0 + 3) * DF + tid] = f2bf(a3);
    __syncthreads();
  }
}

// ---------------- generic [rows,128] @ [128,128]^T (+bias), bf16 weights in LDS ----------------
__global__ __launch_bounds__(128) void k_gemm128(
    const float* __restrict__ A, const float* __restrict__ W,
    const float* __restrict__ bias, float* __restrict__ out, int rows) {
  __shared__ unsigned Wt2[64 * DF];  // Wt2[k2*128+d] = (W[d][2k2], W[d][2k2+1]) bf16 pair
  __shared__ float ar[4][DF];
  int tid = threadIdx.x;
  for (int i = tid; i < 64 * DF; i += 128) {
    int k2 = i >> 7, d = i & 127;
    Wt2[i] = pack2bf(W[(size_t)d * DF + 2 * k2], W[(size_t)d * DF + 2 * k2 + 1]);
  }
  float bb = bias ? bias[tid] : 0.f;
  __syncthreads();
  for (int r0 = blockIdx.x * 4; r0 < rows; r0 += gridDim.x * 4) {
#pragma unroll
    for (int j = 0; j < 4; ++j) ar[j][tid] = A[(size_t)(r0 + j) * DF + tid];
    __syncthreads();
    float a0 = bb, a1 = bb, a2 = bb, a3 = bb;
#pragma unroll 8
    for (int k2 = 0; k2 < 64; ++k2) {
      unsigned u = Wt2[k2 * DF + tid];
      float wlo = __uint_as_float(u << 16);
      float whi = __uint_as_float(u & 0xffff0000u);
      float2 x0 = *reinterpret_cast<const float2*>(&ar[0][2 * k2]);
      float2 x1 = *reinterpret_cast<const float2*>(&ar[1][2 * k2]);
      float2 x2 = *reinterpret_cast<const float2*>(&ar[2][2 * k2]);
      float2 x3 = *reinterpret_cast<const float2*>(&ar[3][2 * k2]);
      a0 = fmaf(x0.x, wlo, fmaf(x0.y, whi, a0));
      a1 = fmaf(x1.x, wlo, fmaf(x1.y, whi, a1));
      a2 = fmaf(x2.x, wlo, fmaf(x2.y, whi, a2));
      a3 = fmaf(x3.x, wlo, fmaf(x3.y, whi, a3));
    }
    out[(size_t)r0 * DF + tid] = a0;
    out[(size_t)(r0 + 1) * DF + tid] = a1;
    out[(size_t)(r0 + 2) * DF + tid] = a2;
    out[(size_t)(r0 + 3) * DF + tid] = a3;
    __syncthreads();
  }
}

// ---------------- layer: m = hV[src]*sigmoid(e); segment_max -> agg ----------------
__global__ __launch_bounds__(256) void k_edge_max(
    const float* __restrict__ hV, const unsigned short* __restrict__ e0u,
    const int* __restrict__ src, const int* __restrict__ dst,
    unsigned* __restrict__ agg_u, long long total) {
  long long i = (long long)blockIdx.x * blockDim.x + threadIdx.x;
  long long st = (long long)gridDim.x * blockDim.x;
  for (; i < total; i += st) {
    int e = (int)(i >> 7), d = (int)(i & 127);
    float m = hV[(size_t)src[e] * DF + d] * sigm(bf2f(e0u[i]));
    atomicMax(&agg_u[(size_t)dst[e] * DF + d], enc_f(m));
  }
}

// tmp_h = hU + decode(agg); accumulate node BN stats
__global__ __launch_bounds__(128) void k_node_pre_bn(
    float* __restrict__ hU, const unsigned* __restrict__ agg_u,
    float* __restrict__ stat, int rows) {
  int tid = threadIdx.x;
  float ps = 0.f, pq = 0.f;
  for (int n = blockIdx.x; n < rows; n += gridDim.x) {
    size_t idx = (size_t)n * DF + tid;
    unsigned k = agg_u[idx];
    float a = (k == ENC_NEGINF) ? 0.f : dec_f(k);
    float t = hU[idx] + a;
    hU[idx] = t;
    ps += t; pq += t * t;
  }
  atomicAdd(&stat[tid], ps);
  atomicAdd(&stat[128 + tid], pq);
}

// x = e0 @ As^T + hB[dst] + hC[src]
// apply==0: accumulate BN stats only.  apply==1: e0 += relu(bn(x)) (recompute x).
__global__ __launch_bounds__(128) void k_edge_pass(
    unsigned short* __restrict__ e0u, const float* __restrict__ As,
    const float* __restrict__ hB, const float* __restrict__ hC,
    const int* __restrict__ src, const int* __restrict__ dst,
    float* __restrict__ stat, int apply, int rows) {
  __shared__ unsigned Wt2[64 * DF];
  __shared__ float ar[4][DF];
  __shared__ int sidx[8];
  int tid = threadIdx.x;
  for (int i = tid; i < 64 * DF; i += 128) {
    int k2 = i >> 7, d = i & 127;
    Wt2[i] = pack2bf(As[(size_t)d * DF + 2 * k2], As[(size_t)d * DF + 2 * k2 + 1]);
  }
  float sm = stat[768 + tid];  // valid only when apply==1
  float si = stat[896 + tid];
  __syncthreads();
  float ps = 0.f, pq = 0.f;
  for (int r0 = blockIdx.x * 4; r0 < rows; r0 += gridDim.x * 4) {
#pragma unroll
    for (int j = 0; j < 4; ++j) ar[j][tid] = bf2f(e0u[(size_t)(r0 + j) * DF + tid]);
    if (tid < 4) sidx[tid] = src[r0 + tid];
    else if (tid < 8) sidx[tid] = dst[r0 + tid - 4];
    __syncthreads();
    float a0 = hB[(size_t)sidx[4] * DF + tid] + hC[(size_t)sidx[0] * DF + tid];
    float a1 = hB[(size_t)sidx[5] * DF + tid] + hC[(size_t)sidx[1] * DF + tid];
    float a2 = hB[(size_t)sidx[6] * DF + tid] + hC[(size_t)sidx[2] * DF + tid];
    float a3 = hB[(size_t)sidx[7] * DF + tid] + hC[(size_t)sidx[3] * DF + tid];
#pragma unroll 8
    for (int k2 = 0; k2 < 64; ++k2) {
      unsigned u = Wt2[k2 * DF + tid];
      float wlo = __uint_as_float(u << 16);
      float whi = __uint_as_float(u & 0xffff0000u);
      float2 x0 = *reinterpret_cast<const float2*>(&ar[0][2 * k2]);
      float2 x1 = *reinterpret_cast<const float2*>(&ar[1][2 * k2]);
      float2 x2 = *reinterpret_cast<const float2*>(&ar[2][2 * k2]);
      float2 x3 = *reinterpret_cast<const float2*>(&ar[3][2 * k2]);
      a0 = fmaf(x0.x, wlo, fmaf(x0.y, whi, a0));
      a1 = fmaf(x1.x, wlo, fmaf(x1.y, whi, a1));
      a2 = fmaf(x2.x, wlo, fmaf(x2.y, whi, a2));
      a3 = fmaf(x3.x, wlo, fmaf(x3.y, whi, a3));
    }
    if (apply) {
      float n0 = ar[0][tid] + fmaxf((a0 - sm) * si, 0.f);
      float n1 = ar[1][tid] + fmaxf((a1 - sm) * si, 0.f);
      float n2 = ar[2][tid] + fmaxf((a2 - sm) * si, 0.f);
      float n3 = ar[3][tid] + fmaxf((a3 - sm) * si, 0.f);
      e0u[(size_t)r0 * DF + tid] = f2bf(n0);
      e0u[(size_t)(r0 + 1) * DF + tid] = f2bf(n1);
      e0u[(size_t)(r0 + 2) * DF + tid] = f2bf(n2);
      e0u[(size_t)(r0 + 3) * DF + tid] = f2bf(n3);
    } else {
      ps += a0 + a1 + a2 + a3;
      pq += a0 * a0 + a1 * a1 + a2 * a2 + a3 * a3;
    }
    __syncthreads();
  }
  if (!apply) {
    atomicAdd(&stat[512 + tid], ps);
    atomicAdd(&stat[640 + tid], pq);
  }
}

// finalize BN stats: node sum/sumsq [0,256) -> mean [256,384), inv [384,512)
//                    edge sum/sumsq [512,768) -> mean [768,896), inv [896,1024)
__global__ void k_bn_finalize(float* __restrict__ stat, float nN, float nE) {
  int tid = threadIdx.x;
  if (tid < 128) {
    float mean = stat[tid] / nN;
    float var = stat[128 + tid] / nN - mean * mean;
    stat[256 + tid] = mean;
    stat[384 + tid] = rsqrtf(fmaxf(var, 0.f) + 1e-5f);
  } else {
    int d = tid - 128;
    float mean = stat[512 + d] / nE;
    float var = stat[640 + d] / nE - mean * mean;
    stat[768 + d] = mean;
    stat[896 + d] = rsqrtf(fmaxf(var, 0.f) + 1e-5f);
  }
}

__global__ __launch_bounds__(256) void k_node_update(
    float* __restrict__ h0, const float* __restrict__ hU,
    const float* __restrict__ stat, long long total) {
  long long i = (long long)blockIdx.x * blockDim.x + threadIdx.x;
  long long st = (long long)gridDim.x * blockDim.x;
  for (; i < total; i += st) {
    int d = (int)(i & 127);
    float t = (hU[i] - stat[256 + d]) * stat[384 + d];
    h0[i] += fmaxf(t, 0.f);
  }
}

// ---------------- GATv2 ----------------
__global__ __launch_bounds__(256) void k_gat_score(
    const float* __restrict__ fs, const float* __restrict__ fd,
    const int* __restrict__ src, const int* __restrict__ dst,
    const float* __restrict__ attn, float* __restrict__ score,
    unsigned* __restrict__ smax_u, long long total) {
  long long i = (long long)blockIdx.x * blockDim.x + threadIdx.x;
  long long st = (long long)gridDim.x * blockDim.x;
  for (; i < total; i += st) {
    int e = (int)(i >> 3), m = (int)(i & 7);
    int s = src[e], dn = dst[e];
    const float* ps = fs + (size_t)s * DF + m * 16;
    const float* pd = fd + (size_t)dn * DF + m * 16;
    const float* pa = attn + m * 16;
    float acc = 0.f;
#pragma unroll
    for (int k = 0; k < 16; ++k) {
      float z = ps[k] + pd[k];
      z = (z > 0.f) ? z : 0.2f * z;
      acc = fmaf(z, pa[k], acc);
    }
    score[i] = acc;
    atomicMax(&smax_u[(size_t)dn * 8 + m], enc_f(acc));
  }
}

__global__ __launch_bounds__(256) void k_gat_p(
    float* __restrict__ score, const unsigned* __restrict__ smax_u,
    const int* __restrict__ dst, float* __restrict__ denom, long long total) {
  long long i = (long long)blockIdx.x * blockDim.x + threadIdx.x;
  long long st = (long long)gridDim.x * blockDim.x;
  for (; i < total; i += st) {
    int e = (int)(i >> 3), m = (int)(i & 7);
    int dn = dst[e];
    float p = __expf(score[i] - dec_f(smax_u[(size_t)dn * 8 + m]));
    score[i] = p;
    atomicAdd(&denom[(size_t)dn * 8 + m], p);
  }
}

__global__ __launch_bounds__(256) void k_gat_rst(
    const float* __restrict__ score, const float* __restrict__ denom,
    const float* __restrict__ fs, const int* __restrict__ src,
    const int* __restrict__ dst, float* __restrict__ rst, long long total) {
  long long i = (long long)blockIdx.x * blockDim.x + threadIdx.x;
  long long st = (long long)gridDim.x * blockDim.x;
  for (; i < total; i += st) {
    int e = (int)(i >> 7), d = (int)(i & 127), m = d >> 4;
    int s = src[e], dn = dst[e];
    float a = score[(size_t)e * 8 + m] / denom[(size_t)dn * 8 + m];
    atomicAdd(&rst[(size_t)dn * DF + d], a * fs[(size_t)s * DF + d]);
  }
}

// bias2 = O_b + gat_bias @ O_w^T
__global__ void k_bias2(const float* __restrict__ gat_bias,
                        const float* __restrict__ O_w,
                        const float* __restrict__ O_b, float* __restrict__ bias2) {
  int d = threadIdx.x;
  float acc = O_b[d];
  for (int k = 0; k < DF; ++k) acc = fmaf(gat_bias[k], O_w[(size_t)d * DF + k], acc);
  bias2[d] = acc;
}

// ---------------- readout ----------------
__global__ __launch_bounds__(128) void k_moy(
    const float* __restrict__ h2, const int* __restrict__ ng,
    float* __restrict__ moy, float* __restrict__ cnt, int rows) {
  int tid = threadIdx.x;
  int per = (rows + gridDim.x - 1) / gridDim.x;
  int n0 = blockIdx.x * per;
  int n1 = min(rows, n0 + per);
  if (n0 >= n1) return;
  int cur = ng[n0];
  float acc = 0.f; int c = 0;
  for (int n = n0; n < n1; ++n) {
    int g = ng[n];
    if (g != cur) {
      atomicAdd(&moy[cur * DF + tid], acc);
      if (tid == 0) atomicAdd(&cnt[cur], (float)c);
      acc = 0.f; c = 0; cur = g;
    }
    acc += h2[(size_t)n * DF + tid];
    ++c;
  }
  atomicAdd(&moy[cur * DF + tid], acc);
  if (tid == 0) atomicAdd(&cnt[cur], (float)c);
}

__global__ void k_moy_div(float* __restrict__ moy, const float* __restrict__ cnt) {
  moy[blockIdx.x * DF + threadIdx.x] /= cnt[blockIdx.x];
}

// fused head: y = relu([moy|h_src|h_dst] @ W1^T + b1); out = sigmoid(y.W2 + b2)
__global__ __launch_bounds__(512) void k_final(
    const float* __restrict__ h2, const float* __restrict__ moy,
    const int* __restrict__ src, const int* __restrict__ dst,
    const int* __restrict__ eg, const float* __restrict__ W1,
    const float* __restrict__ W1b, const float* __restrict__ W2,
    const float* __restrict__ W2b, float* __restrict__ out, int E) {
  __shared__ unsigned Wt2[192 * DF];  // bf16 pairs: Wt2[k2*128+d] = (W1[d][2k2], W1[d][2k2+1])
  __shared__ float xrow[4][384];
  __shared__ float red[4][2];
  int tid = threadIdx.x;
  int sub = tid >> 7, d = tid & 127;
  for (int i = tid; i < 192 * DF; i += 512) {
    int k2 = i >> 7, dd = i & 127;
    Wt2[i] = pack2bf(W1[(size_t)dd * 384 + 2 * k2], W1[(size_t)dd * 384 + 2 * k2 + 1]);
  }
  float b1 = W1b[d];
  float w2 = W2[d];
  float w2b = W2b[0];
  __syncthreads();
  for (long long i0 = (long long)blockIdx.x * 4; i0 < E; i0 += (long long)gridDim.x * 4) {
    long long i = i0 + sub;  // E % 4 == 0
    int s = src[i], dn = dst[i], g = eg[i];
    xrow[sub][d] = moy[g * DF + d];
    xrow[sub][DF + d] = h2[(size_t)s * DF + d];
    xrow[sub][2 * DF + d] = h2[(size_t)dn * DF + d];
    __syncthreads();
    float acc = b1;
    const float* xr = xrow[sub];
#pragma unroll 8
    for (int k2 = 0; k2 < 192; ++k2) {
      unsigned u = Wt2[k2 * DF + d];
      float2 xp = *reinterpret_cast<const float2*>(xr + 2 * k2);
      acc = fmaf(xp.x, __uint_as_float(u << 16), acc);
      acc = fmaf(xp.y, __uint_as_float(u & 0xffff0000u), acc);
    }
    float v = fmaxf(acc, 0.f) * w2;
#pragma unroll
    for (int off = 32; off > 0; off >>= 1) v += __shfl_down(v, off, 64);
    if ((tid & 63) == 0) red[sub][(tid >> 6) & 1] = v;
    __syncthreads();
    if (d == 0) {
      float t = red[sub][0] + red[sub][1] + w2b;
      out[i] = 1.f / (1.f + __expf(-t));
    }
    __syncthreads();
  }
}

extern "C" void kernel_launch(void* const* d_in, const int* in_sizes, int n_in,
                              void* d_out, int out_size, void* d_ws, size_t ws_size,
                              hipStream_t stream) {
  const float* h_in = (const float*)d_in[0];
  const float* e_in = (const float*)d_in[1];
  const int* src = (const int*)d_in[2];
  const int* dst = (const int*)d_in[3];
  const int* node_graph = (const int*)d_in[4];
  const int* edge_graph = (const int*)d_in[5];
  const float* emb_n_w = (const float*)d_in[6];
  const float* emb_n_b = (const float*)d_in[7];
  const float* emb_e_w = (const float*)d_in[8];
  const float* emb_e_b = (const float*)d_in[9];
  const float* Us = (const float*)d_in[10];
  const float* Vs = (const float*)d_in[11];
  const float* As = (const float*)d_in[12];
  const float* Bs = (const float*)d_in[13];
  const float* Cs = (const float*)d_in[14];
  const float* gat_src_w = (const float*)d_in[15];
  const float* gat_src_b = (const float*)d_in[16];
  const float* gat_dst_w = (const float*)d_in[17];
  const float* gat_dst_b = (const float*)d_in[18];
  const float* gat_attn = (const float*)d_in[19];
  const float* gat_bias = (const float*)d_in[20];
  const float* O_w = (const float*)d_in[21];
  const float* O_b = (const float*)d_in[22];
  const float* W1_w = (const float*)d_in[23];
  const float* W1_b = (const float*)d_in[24];
  const float* W2_w = (const float*)d_in[25];
  const float* W2_b = (const float*)d_in[26];
  float* out = (float*)d_out;

  const int N = in_sizes[0] / 64;   // 30000
  const int E = in_sizes[1] / 16;   // 360000

  // workspace layout (all 256B-aligned sizes), total ~198 MB
  const size_t sz_e0 = (size_t)E * DF * sizeof(unsigned short);  // 92.16 MB
  const size_t sz_node = (size_t)N * DF * sizeof(float);         // 15.36 MB
  const size_t sz_score = (size_t)E * 8 * sizeof(float);         // 11.52 MB
  const size_t sz_n8 = (size_t)N * 8 * sizeof(float);            // 0.96 MB
  const size_t sz_misc = 4096 * sizeof(float);
  const size_t needed = sz_e0 + 6 * sz_node + sz_score + 2 * sz_n8 + sz_misc;
  if (ws_size < needed) {  // diagnostic: fill out with -1.0 so absmax ~1.58 (not a crash)
    k_fill_u32<<<256, 256, 0, stream>>>((unsigned*)out, 0xBF800000u, (long long)out_size);
    return;
  }

  char* wp = (char*)d_ws;
  auto alloc = [&](size_t bytes) { void* p = wp; wp += bytes; return p; };
  unsigned short* e0u = (unsigned short*)alloc(sz_e0);
  float* h0 = (float*)alloc(sz_node);
  float* hV = (float*)alloc(sz_node);
  float* hU = (float*)alloc(sz_node);
  float* hB = (float*)alloc(sz_node);
  float* hC = (float*)alloc(sz_node);
  unsigned* agg_u = (unsigned*)alloc(sz_node);
  float* score = (float*)alloc(sz_score);
  unsigned* smax_u = (unsigned*)alloc(sz_n8);
  float* denom = (float*)alloc(sz_n8);
  float* misc = (float*)alloc(sz_misc);
  float* stat = misc;          // 1024
  float* bias2 = misc + 1024;  // 128
  float* moy = misc + 1152;    // 1024
  float* cnt = misc + 2176;    // 8

  // embeddings
  k_node_embed<<<2048, 128, 0, stream>>>(h_in, emb_n_w, emb_n_b, h0, N);
  k_edge_embed<<<4096, 128, 0, stream>>>(e_in, emb_e_w, emb_e_b, e0u, E);

  for (int l = 0; l < 3; ++l) {
    const float* Ul = Us + (size_t)l * DF * DF;
    const float* Vl = Vs + (size_t)l * DF * DF;
    const float* Al = As + (size_t)l * DF * DF;
    const float* Bl = Bs + (size_t)l * DF * DF;
    const float* Cl = Cs + (size_t)l * DF * DF;
    k_gemm128<<<2048, 128, 0, stream>>>(h0, Vl, nullptr, hV, N);
    k_gemm128<<<2048, 128, 0, stream>>>(h0, Ul, nullptr, hU, N);
    k_gemm128<<<2048, 128, 0, stream>>>(h0, Bl, nullptr, hB, N);
    k_gemm128<<<2048, 128, 0, stream>>>(h0, Cl, nullptr, hC, N);
    k_fill_u32<<<4096, 256, 0, stream>>>(agg_u, ENC_NEGINF, (long long)N * DF);
    k_fill_u32<<<4, 256, 0, stream>>>((unsigned*)stat, 0u, 1024);
    k_edge_max<<<4096, 256, 0, stream>>>(hV, e0u, src, dst, agg_u, (long long)E * DF);
    k_node_pre_bn<<<512, 128, 0, stream>>>(hU, agg_u, stat, N);
    k_edge_pass<<<4096, 128, 0, stream>>>(e0u, Al, hB, hC, src, dst, stat, 0, E);
    k_bn_finalize<<<1, 256, 0, stream>>>(stat, (float)N, (float)E);
    k_node_update<<<2048, 256, 0, stream>>>(h0, hU, stat, (long long)N * DF);
    k_edge_pass<<<4096, 128, 0, stream>>>(e0u, Al, hB, hC, src, dst, stat, 1, E);
  }

  // GATv2
  k_gemm128<<<2048, 128, 0, stream>>>(h0, gat_src_w, gat_src_b, hV, N);  // fs
  k_gemm128<<<2048, 128, 0, stream>>>(h0, gat_dst_w, gat_dst_b, hB, N);  // fd
  float* rst = (float*)agg_u;
  k_fill_u32<<<256, 256, 0, stream>>>(smax_u, ENC_NEGINF, (long long)N * 8);
  k_fill_u32<<<256, 256, 0, stream>>>((unsigned*)denom, 0u, (long long)N * 8);
  k_fill_u32<<<4096, 256, 0, stream>>>((unsigned*)rst, 0u, (long long)N * DF);
  k_fill_u32<<<2, 256, 0, stream>>>((unsigned*)moy, 0u, 1032);  // moy + cnt
  k_gat_score<<<4096, 256, 0, stream>>>(hV, hB, src, dst, gat_attn, score, smax_u,
                                        (long long)E * 8);
  k_gat_p<<<4096, 256, 0, stream>>>(score, smax_u, dst, denom, (long long)E * 8);
  k_gat_rst<<<4096, 256, 0, stream>>>(score, denom, hV, src, dst, rst, (long long)E * DF);
  k_bias2<<<1, 128, 0, stream>>>(gat_bias, O_w, O_b, bias2);
  k_gemm128<<<2048, 128, 0, stream>>>(rst, O_w, bias2, hU, N);  // h2

  // readout
  k_moy<<<128, 128, 0, stream>>>(hU, node_graph, moy, cnt, N);
  k_moy_div<<<8, 128, 0, stream>>>(moy, cnt);
  k_final<<<512, 512, 0, stream>>>(hU, moy, src, dst, edge_graph, W1_w, W1_b, W2_w,
                                   W2_b, out, E);
}

// Round 3
// 2467.052 us; speedup vs baseline: 2.4841x; 2.4841x over previous
//
#include <hip/hip_runtime.h>

#define DF 128

typedef __attribute__((ext_vector_type(8))) short bf16x8;
typedef __attribute__((ext_vector_type(4))) float f32x4;

constexpr unsigned ENC_NEGINF = 0x007FFFFFu;  // enc(-inf)

__device__ __forceinline__ unsigned enc_f(float f) {
  unsigned u = __float_as_uint(f);
  return (u & 0x80000000u) ? ~u : (u | 0x80000000u);
}
__device__ __forceinline__ float dec_f(unsigned k) {
  unsigned u = (k & 0x80000000u) ? (k & 0x7FFFFFFFu) : ~k;
  return __uint_as_float(u);
}
__device__ __forceinline__ float sigm(float x) { return 1.f / (1.f + __expf(-x)); }
__device__ __forceinline__ unsigned short f2bf(float f) {  // RNE f32->bf16
  unsigned u = __float_as_uint(f);
  u += 0x7FFFu + ((u >> 16) & 1u);
  return (unsigned short)(u >> 16);
}
__device__ __forceinline__ float bf2f(unsigned short u) {
  return __uint_as_float(((unsigned)u) << 16);
}

// load 8 consecutive f32 (32B-aligned) -> bf16x8
__device__ __forceinline__ bf16x8 cvt8(const float* __restrict__ p) {
  float4 a = *(const float4*)p;
  float4 b = *(const float4*)(p + 4);
  bf16x8 r;
  r[0] = (short)f2bf(a.x); r[1] = (short)f2bf(a.y);
  r[2] = (short)f2bf(a.z); r[3] = (short)f2bf(a.w);
  r[4] = (short)f2bf(b.x); r[5] = (short)f2bf(b.y);
  r[6] = (short)f2bf(b.z); r[7] = (short)f2bf(b.w);
  return r;
}

// ---------------- generic fill ----------------
__global__ void k_fill_u32(unsigned* __restrict__ p, unsigned v, long long n) {
  long long i = (long long)blockIdx.x * blockDim.x + threadIdx.x;
  long long st = (long long)gridDim.x * blockDim.x;
  for (; i < n; i += st) p[i] = v;
}

// ---------------- embeddings ----------------
__global__ __launch_bounds__(128) void k_node_embed(
    const float* __restrict__ hin, const float* __restrict__ w,
    const float* __restrict__ b, float* __restrict__ h0, int rows) {
  __shared__ float Wt[64 * DF];
  __shared__ float ar[4][64];
  int tid = threadIdx.x;
  for (int i = tid; i < 64 * DF; i += 128) Wt[(i & 63) * DF + (i >> 6)] = w[i];
  float bb = b[tid];
  __syncthreads();
  for (int r0 = blockIdx.x * 4; r0 < rows; r0 += gridDim.x * 4) {
    for (int i = tid; i < 256; i += 128) ar[i >> 6][i & 63] = hin[(size_t)r0 * 64 + i];
    __syncthreads();
    float a0 = bb, a1 = bb, a2 = bb, a3 = bb;
#pragma unroll 8
    for (int k = 0; k < 64; ++k) {
      float wv = Wt[k * DF + tid];
      a0 = fmaf(ar[0][k], wv, a0); a1 = fmaf(ar[1][k], wv, a1);
      a2 = fmaf(ar[2][k], wv, a2); a3 = fmaf(ar[3][k], wv, a3);
    }
    h0[(size_t)r0 * DF + tid] = a0;
    h0[(size_t)(r0 + 1) * DF + tid] = a1;
    h0[(size_t)(r0 + 2) * DF + tid] = a2;
    h0[(size_t)(r0 + 3) * DF + tid] = a3;
    __syncthreads();
  }
}

__global__ __launch_bounds__(128) void k_edge_embed(
    const float* __restrict__ ein, const float* __restrict__ w,
    const float* __restrict__ b, unsigned short* __restrict__ e0u, int rows) {
  __shared__ float Wt[16 * DF];
  __shared__ float ar[4][16];
  int tid = threadIdx.x;
  for (int i = tid; i < 16 * DF; i += 128) Wt[(i & 15) * DF + (i >> 4)] = w[i];
  float bb = b[tid];
  __syncthreads();
  for (int r0 = blockIdx.x * 4; r0 < rows; r0 += gridDim.x * 4) {
    if (tid < 64) ar[tid >> 4][tid & 15] = ein[(size_t)r0 * 16 + tid];
    __syncthreads();
    float a0 = bb, a1 = bb, a2 = bb, a3 = bb;
#pragma unroll
    for (int k = 0; k < 16; ++k) {
      float wv = Wt[k * DF + tid];
      a0 = fmaf(ar[0][k], wv, a0); a1 = fmaf(ar[1][k], wv, a1);
      a2 = fmaf(ar[2][k], wv, a2); a3 = fmaf(ar[3][k], wv, a3);
    }
    e0u[(size_t)r0 * DF + tid] = f2bf(a0);
    e0u[(size_t)(r0 + 1) * DF + tid] = f2bf(a1);
    e0u[(size_t)(r0 + 2) * DF + tid] = f2bf(a2);
    e0u[(size_t)(r0 + 3) * DF + tid] = f2bf(a3);
    __syncthreads();
  }
}

// ---------------- MFMA [rows,128] @ W[128,128]^T (+bias) -> f32 out ----------------
// 8 waves/block, 128-row tiles, 16 rows/wave.
// frag layout (16x16x32): A: lane holds A[l&15][(l>>4)*8+i]; B: B[(l>>4)*8+i][l&15];
// C/D: col=l&15, row=(l>>4)*4+reg.
__global__ __launch_bounds__(512) void k_gemm_mfma(
    const float* __restrict__ A, const float* __restrict__ W,
    const float* __restrict__ bias, float* __restrict__ out, int rows) {
  __shared__ short Wl[128 * 136];  // bf16, row-padded by 8 (2-way bank, free)
  int tid = threadIdx.x;
  for (int i = tid; i < 16384; i += 512)
    Wl[(i >> 7) * 136 + (i & 127)] = (short)f2bf(W[i]);
  __syncthreads();
  int wid = tid >> 6, lane = tid & 63, q = lane >> 4, m = lane & 15;
  int ntiles = (rows + 127) >> 7;
  for (int t = blockIdx.x; t < ntiles; t += gridDim.x) {
    int r0 = t * 128 + wid * 16;
    int rr = r0 + m;
    if (rr >= rows) rr = rows - 1;
    const float* ap = A + (size_t)rr * DF + q * 8;
    bf16x8 a[4];
#pragma unroll
    for (int ks = 0; ks < 4; ++ks) a[ks] = cvt8(ap + 32 * ks);
#pragma unroll
    for (int ct = 0; ct < 8; ++ct) {
      f32x4 acc = {0.f, 0.f, 0.f, 0.f};
#pragma unroll
      for (int ks = 0; ks < 4; ++ks) {
        bf16x8 b = *(const bf16x8*)&Wl[(ct * 16 + m) * 136 + q * 8 + 32 * ks];
        acc = __builtin_amdgcn_mfma_f32_16x16x32_bf16(a[ks], b, acc, 0, 0, 0);
      }
      int col = ct * 16 + m;
      float bb = bias ? bias[col] : 0.f;
#pragma unroll
      for (int j = 0; j < 4; ++j) {
        int row = r0 + q * 4 + j;
        if (row < rows) out[(size_t)row * DF + col] = acc[j] + bb;
      }
    }
  }
}

// ---------------- MFMA edge pass: x = e@As^T + hB[dst] + hC[src] ----------------
// APPLY=0: accumulate column sum/sumsq into stat[512..768).
// APPLY=1: e0u += relu((x - mean)*inv), bf16.
template <int APPLY>
__global__ __launch_bounds__(512) void k_edge_mfma(
    unsigned short* __restrict__ e0u, const float* __restrict__ As,
    const float* __restrict__ hB, const float* __restrict__ hC,
    const int* __restrict__ src, const int* __restrict__ dst,
    float* __restrict__ stat, int E) {
  __shared__ short Wl[128 * 136];
  __shared__ float xt[8][16 * 132];  // per-wave 16x128 f32 tile, pad 4
  int tid = threadIdx.x;
  for (int i = tid; i < 16384; i += 512)
    Wl[(i >> 7) * 136 + (i & 127)] = (short)f2bf(As[i]);
  int wid = tid >> 6, lane = tid & 63, q = lane >> 4, m = lane & 15;
  float* xw = xt[wid];
  float ps0 = 0.f, ps1 = 0.f, pq0 = 0.f, pq1 = 0.f;
  __syncthreads();
  int ntiles = (E + 127) >> 7;
  for (int t = blockIdx.x; t < ntiles; t += gridDim.x) {
    int r0 = t * 128 + wid * 16;
    int edge = r0 + m;
    bool ok = edge < E;
    int ec = ok ? edge : E - 1;
    const unsigned short* ep = e0u + (size_t)ec * DF + q * 8;
    bf16x8 a[4];
#pragma unroll
    for (int ks = 0; ks < 4; ++ks) a[ks] = *(const bf16x8*)(ep + 32 * ks);
#pragma unroll
    for (int ct = 0; ct < 8; ++ct) {
      f32x4 acc = {0.f, 0.f, 0.f, 0.f};
#pragma unroll
      for (int ks = 0; ks < 4; ++ks) {
        bf16x8 b = *(const bf16x8*)&Wl[(ct * 16 + m) * 136 + q * 8 + 32 * ks];
        acc = __builtin_amdgcn_mfma_f32_16x16x32_bf16(a[ks], b, acc, 0, 0, 0);
      }
#pragma unroll
      for (int j = 0; j < 4; ++j) xw[(q * 4 + j) * 132 + ct * 16 + m] = acc[j];
    }
    __syncthreads();
    // row-layout phase: lane handles row m, cols q*8+32ks..+8
    int sidx = src[ec], didx = dst[ec];
    const float* pb = hB + (size_t)didx * DF;
    const float* pc = hC + (size_t)sidx * DF;
#pragma unroll
    for (int ks = 0; ks < 4; ++ks) {
      int c0 = q * 8 + 32 * ks;
      float* xp = &xw[m * 132 + c0];
      float4 x0 = *(float4*)xp;
      float4 x1 = *(float4*)(xp + 4);
      float4 g0 = *(const float4*)(pb + c0);
      float4 g1 = *(const float4*)(pb + c0 + 4);
      float4 h0v = *(const float4*)(pc + c0);
      float4 h1v = *(const float4*)(pc + c0 + 4);
      x0.x += g0.x + h0v.x; x0.y += g0.y + h0v.y;
      x0.z += g0.z + h0v.z; x0.w += g0.w + h0v.w;
      x1.x += g1.x + h1v.x; x1.y += g1.y + h1v.y;
      x1.z += g1.z + h1v.z; x1.w += g1.w + h1v.w;
      if (APPLY) {
        float4 mm0 = *(const float4*)&stat[768 + c0];
        float4 mm1 = *(const float4*)&stat[768 + c0 + 4];
        float4 iv0 = *(const float4*)&stat[896 + c0];
        float4 iv1 = *(const float4*)&stat[896 + c0 + 4];
        bf16x8 nv;
        nv[0] = (short)f2bf(bf2f((unsigned short)a[ks][0]) + fmaxf((x0.x - mm0.x) * iv0.x, 0.f));
        nv[1] = (short)f2bf(bf2f((unsigned short)a[ks][1]) + fmaxf((x0.y - mm0.y) * iv0.y, 0.f));
        nv[2] = (short)f2bf(bf2f((unsigned short)a[ks][2]) + fmaxf((x0.z - mm0.z) * iv0.z, 0.f));
        nv[3] = (short)f2bf(bf2f((unsigned short)a[ks][3]) + fmaxf((x0.w - mm0.w) * iv0.w, 0.f));
        nv[4] = (short)f2bf(bf2f((unsigned short)a[ks][4]) + fmaxf((x1.x - mm1.x) * iv1.x, 0.f));
        nv[5] = (short)f2bf(bf2f((unsigned short)a[ks][5]) + fmaxf((x1.y - mm1.y) * iv1.y, 0.f));
        nv[6] = (short)f2bf(bf2f((unsigned short)a[ks][6]) + fmaxf((x1.z - mm1.z) * iv1.z, 0.f));
        nv[7] = (short)f2bf(bf2f((unsigned short)a[ks][7]) + fmaxf((x1.w - mm1.w) * iv1.w, 0.f));
        if (ok) *(bf16x8*)(e0u + (size_t)ec * DF + c0) = nv;
      } else {
        if (!ok) {
          x0.x = x0.y = x0.z = x0.w = 0.f;
          x1.x = x1.y = x1.z = x1.w = 0.f;
        }
        *(float4*)xp = x0;
        *(float4*)(xp + 4) = x1;
      }
    }
    if (!APPLY) {
      __syncthreads();
      // column stats: lane handles cols 2*lane, 2*lane+1 of this wave's tile
#pragma unroll 4
      for (int r = 0; r < 16; ++r) {
        float2 v = *(float2*)&xw[r * 132 + 2 * lane];
        ps0 += v.x; ps1 += v.y;
        pq0 += v.x * v.x; pq1 += v.y * v.y;
      }
    }
    __syncthreads();
  }
  if (!APPLY) {
    atomicAdd(&stat[512 + 2 * lane], ps0);
    atomicAdd(&stat[512 + 2 * lane + 1], ps1);
    atomicAdd(&stat[640 + 2 * lane], pq0);
    atomicAdd(&stat[640 + 2 * lane + 1], pq1);
  }
}

// ---------------- layer: m = hV[src]*sigmoid(e); segment_max -> agg ----------------
__global__ __launch_bounds__(256) void k_edge_max(
    const float* __restrict__ hV, const unsigned short* __restrict__ e0u,
    const int* __restrict__ src, const int* __restrict__ dst,
    unsigned* __restrict__ agg_u, long long total) {
  long long i = (long long)blockIdx.x * blockDim.x + threadIdx.x;
  long long st = (long long)gridDim.x * blockDim.x;
  for (; i < total; i += st) {
    int e = (int)(i >> 7), d = (int)(i & 127);
    float m = hV[(size_t)src[e] * DF + d] * sigm(bf2f(e0u[i]));
    atomicMax(&agg_u[(size_t)dst[e] * DF + d], enc_f(m));
  }
}

// tmp_h = hU + decode(agg); accumulate node BN stats
__global__ __launch_bounds__(128) void k_node_pre_bn(
    float* __restrict__ hU, const unsigned* __restrict__ agg_u,
    float* __restrict__ stat, int rows) {
  int tid = threadIdx.x;
  float ps = 0.f, pq = 0.f;
  for (int n = blockIdx.x; n < rows; n += gridDim.x) {
    size_t idx = (size_t)n * DF + tid;
    unsigned k = agg_u[idx];
    float a = (k == ENC_NEGINF) ? 0.f : dec_f(k);
    float t = hU[idx] + a;
    hU[idx] = t;
    ps += t; pq += t * t;
  }
  atomicAdd(&stat[tid], ps);
  atomicAdd(&stat[128 + tid], pq);
}

// finalize BN stats
__global__ void k_bn_finalize(float* __restrict__ stat, float nN, float nE) {
  int tid = threadIdx.x;
  if (tid < 128) {
    float mean = stat[tid] / nN;
    float var = stat[128 + tid] / nN - mean * mean;
    stat[256 + tid] = mean;
    stat[384 + tid] = rsqrtf(fmaxf(var, 0.f) + 1e-5f);
  } else {
    int d = tid - 128;
    float mean = stat[512 + d] / nE;
    float var = stat[640 + d] / nE - mean * mean;
    stat[768 + d] = mean;
    stat[896 + d] = rsqrtf(fmaxf(var, 0.f) + 1e-5f);
  }
}

__global__ __launch_bounds__(256) void k_node_update(
    float* __restrict__ h0, const float* __restrict__ hU,
    const float* __restrict__ stat, long long total) {
  long long i = (long long)blockIdx.x * blockDim.x + threadIdx.x;
  long long st = (long long)gridDim.x * blockDim.x;
  for (; i < total; i += st) {
    int d = (int)(i & 127);
    float t = (hU[i] - stat[256 + d]) * stat[384 + d];
    h0[i] += fmaxf(t, 0.f);
  }
}

// ---------------- GATv2 ----------------
__global__ __launch_bounds__(256) void k_gat_score(
    const float* __restrict__ fs, const float* __restrict__ fd,
    const int* __restrict__ src, const int* __restrict__ dst,
    const float* __restrict__ attn, float* __restrict__ score,
    unsigned* __restrict__ smax_u, long long total) {
  long long i = (long long)blockIdx.x * blockDim.x + threadIdx.x;
  long long st = (long long)gridDim.x * blockDim.x;
  for (; i < total; i += st) {
    int e = (int)(i >> 3), m = (int)(i & 7);
    int s = src[e], dn = dst[e];
    const float* ps = fs + (size_t)s * DF + m * 16;
    const float* pd = fd + (size_t)dn * DF + m * 16;
    const float* pa = attn + m * 16;
    float acc = 0.f;
#pragma unroll
    for (int k = 0; k < 16; ++k) {
      float z = ps[k] + pd[k];
      z = (z > 0.f) ? z : 0.2f * z;
      acc = fmaf(z, pa[k], acc);
    }
    score[i] = acc;
    atomicMax(&smax_u[(size_t)dn * 8 + m], enc_f(acc));
  }
}

__global__ __launch_bounds__(256) void k_gat_p(
    float* __restrict__ score, const unsigned* __restrict__ smax_u,
    const int* __restrict__ dst, float* __restrict__ denom, long long total) {
  long long i = (long long)blockIdx.x * blockDim.x + threadIdx.x;
  long long st = (long long)gridDim.x * blockDim.x;
  for (; i < total; i += st) {
    int e = (int)(i >> 3), m = (int)(i & 7);
    int dn = dst[e];
    float p = __expf(score[i] - dec_f(smax_u[(size_t)dn * 8 + m]));
    score[i] = p;
    atomicAdd(&denom[(size_t)dn * 8 + m], p);
  }
}

__global__ __launch_bounds__(256) void k_gat_rst(
    const float* __restrict__ score, const float* __restrict__ denom,
    const float* __restrict__ fs, const int* __restrict__ src,
    const int* __restrict__ dst, float* __restrict__ rst, long long total) {
  long long i = (long long)blockIdx.x * blockDim.x + threadIdx.x;
  long long st = (long long)gridDim.x * blockDim.x;
  for (; i < total; i += st) {
    int e = (int)(i >> 7), d = (int)(i & 127), m = d >> 4;
    int s = src[e], dn = dst[e];
    float a = score[(size_t)e * 8 + m] / denom[(size_t)dn * 8 + m];
    atomicAdd(&rst[(size_t)dn * DF + d], a * fs[(size_t)s * DF + d]);
  }
}

// bias2 = O_b + gat_bias @ O_w^T
__global__ void k_bias2(const float* __restrict__ gat_bias,
                        const float* __restrict__ O_w,
                        const float* __restrict__ O_b, float* __restrict__ bias2) {
  int d = threadIdx.x;
  float acc = O_b[d];
  for (int k = 0; k < DF; ++k) acc = fmaf(gat_bias[k], O_w[(size_t)d * DF + k], acc);
  bias2[d] = acc;
}

// ---------------- readout ----------------
__global__ __launch_bounds__(128) void k_moy(
    const float* __restrict__ h2, const int* __restrict__ ng,
    float* __restrict__ moy, float* __restrict__ cnt, int rows) {
  int tid = threadIdx.x;
  int per = (rows + gridDim.x - 1) / gridDim.x;
  int n0 = blockIdx.x * per;
  int n1 = min(rows, n0 + per);
  if (n0 >= n1) return;
  int cur = ng[n0];
  float acc = 0.f; int c = 0;
  for (int n = n0; n < n1; ++n) {
    int g = ng[n];
    if (g != cur) {
      atomicAdd(&moy[cur * DF + tid], acc);
      if (tid == 0) atomicAdd(&cnt[cur], (float)c);
      acc = 0.f; c = 0; cur = g;
    }
    acc += h2[(size_t)n * DF + tid];
    ++c;
  }
  atomicAdd(&moy[cur * DF + tid], acc);
  if (tid == 0) atomicAdd(&cnt[cur], (float)c);
}

__global__ void k_moy_div(float* __restrict__ moy, const float* __restrict__ cnt) {
  moy[blockIdx.x * DF + threadIdx.x] /= cnt[blockIdx.x];
}

// ---------------- fused MFMA head ----------------
// y = relu([moy|h_src|h_dst] @ W1^T + b1); out = sigmoid(y.W2 + b2)
__global__ __launch_bounds__(512) void k_final_mfma(
    const float* __restrict__ h2, const float* __restrict__ moy,
    const int* __restrict__ src, const int* __restrict__ dst,
    const int* __restrict__ eg, const float* __restrict__ W1,
    const float* __restrict__ W1b, const float* __restrict__ W2,
    const float* __restrict__ W2b, float* __restrict__ out, int E) {
  __shared__ short Wl[128 * 392];  // bf16 W1, row-padded 384->392
  int tid = threadIdx.x;
  for (int i = tid; i < 49152; i += 512) {
    int r = i / 384, c = i - r * 384;
    Wl[r * 392 + c] = (short)f2bf(W1[i]);
  }
  __syncthreads();
  int wid = tid >> 6, lane = tid & 63, q = lane >> 4, m = lane & 15;
  float w2b = W2b[0];
  int ntiles = (E + 127) >> 7;
  for (int t = blockIdx.x; t < ntiles; t += gridDim.x) {
    int r0 = t * 128 + wid * 16;
    int edge = r0 + m;
    if (edge >= E) edge = E - 1;
    int g = eg[edge], s = src[edge], d = dst[edge];
    const float* b0 = moy + (size_t)g * DF;
    const float* b1p = h2 + (size_t)s * DF;
    const float* b2p = h2 + (size_t)d * DF;
    bf16x8 a[12];
#pragma unroll
    for (int ks = 0; ks < 12; ++ks) {
      int k = ks * 32 + q * 8;
      const float* p = (k < 128) ? (b0 + k) : ((k < 256) ? (b1p + k - 128) : (b2p + k - 256));
      a[ks] = cvt8(p);
    }
    float v0 = 0.f, v1 = 0.f, v2 = 0.f, v3 = 0.f;
#pragma unroll
    for (int ct = 0; ct < 8; ++ct) {
      f32x4 acc = {0.f, 0.f, 0.f, 0.f};
#pragma unroll
      for (int ks = 0; ks < 12; ++ks) {
        bf16x8 b = *(const bf16x8*)&Wl[(ct * 16 + m) * 392 + q * 8 + 32 * ks];
        acc = __builtin_amdgcn_mfma_f32_16x16x32_bf16(a[ks], b, acc, 0, 0, 0);
      }
      int col = ct * 16 + m;
      float bb = W1b[col], ww = W2[col];
      v0 += fmaxf(acc[0] + bb, 0.f) * ww;
      v1 += fmaxf(acc[1] + bb, 0.f) * ww;
      v2 += fmaxf(acc[2] + bb, 0.f) * ww;
      v3 += fmaxf(acc[3] + bb, 0.f) * ww;
    }
#pragma unroll
    for (int mask = 1; mask <= 8; mask <<= 1) {
      v0 += __shfl_xor(v0, mask, 64);
      v1 += __shfl_xor(v1, mask, 64);
      v2 += __shfl_xor(v2, mask, 64);
      v3 += __shfl_xor(v3, mask, 64);
    }
    if (m == 0) {
      int rb = r0 + q * 4;
      if (rb < E) out[rb] = sigm(v0 + w2b);
      if (rb + 1 < E) out[rb + 1] = sigm(v1 + w2b);
      if (rb + 2 < E) out[rb + 2] = sigm(v2 + w2b);
      if (rb + 3 < E) out[rb + 3] = sigm(v3 + w2b);
    }
  }
}

extern "C" void kernel_launch(void* const* d_in, const int* in_sizes, int n_in,
                              void* d_out, int out_size, void* d_ws, size_t ws_size,
                              hipStream_t stream) {
  const float* h_in = (const float*)d_in[0];
  const float* e_in = (const float*)d_in[1];
  const int* src = (const int*)d_in[2];
  const int* dst = (const int*)d_in[3];
  const int* node_graph = (const int*)d_in[4];
  const int* edge_graph = (const int*)d_in[5];
  const float* emb_n_w = (const float*)d_in[6];
  const float* emb_n_b = (const float*)d_in[7];
  const float* emb_e_w = (const float*)d_in[8];
  const float* emb_e_b = (const float*)d_in[9];
  const float* Us = (const float*)d_in[10];
  const float* Vs = (const float*)d_in[11];
  const float* As = (const float*)d_in[12];
  const float* Bs = (const float*)d_in[13];
  const float* Cs = (const float*)d_in[14];
  const float* gat_src_w = (const float*)d_in[15];
  const float* gat_src_b = (const float*)d_in[16];
  const float* gat_dst_w = (const float*)d_in[17];
  const float* gat_dst_b = (const float*)d_in[18];
  const float* gat_attn = (const float*)d_in[19];
  const float* gat_bias = (const float*)d_in[20];
  const float* O_w = (const float*)d_in[21];
  const float* O_b = (const float*)d_in[22];
  const float* W1_w = (const float*)d_in[23];
  const float* W1_b = (const float*)d_in[24];
  const float* W2_w = (const float*)d_in[25];
  const float* W2_b = (const float*)d_in[26];
  float* out = (float*)d_out;

  const int N = in_sizes[0] / 64;   // 30000
  const int E = in_sizes[1] / 16;   // 360000

  const size_t sz_e0 = (size_t)E * DF * sizeof(unsigned short);
  const size_t sz_node = (size_t)N * DF * sizeof(float);
  const size_t sz_score = (size_t)E * 8 * sizeof(float);
  const size_t sz_n8 = (size_t)N * 8 * sizeof(float);
  const size_t sz_misc = 4096 * sizeof(float);
  const size_t needed = sz_e0 + 6 * sz_node + sz_score + 2 * sz_n8 + sz_misc;
  if (ws_size < needed) {
    k_fill_u32<<<256, 256, 0, stream>>>((unsigned*)out, 0xBF800000u, (long long)out_size);
    return;
  }

  char* wp = (char*)d_ws;
  auto alloc = [&](size_t bytes) { void* p = wp; wp += bytes; return p; };
  unsigned short* e0u = (unsigned short*)alloc(sz_e0);
  float* h0 = (float*)alloc(sz_node);
  float* hV = (float*)alloc(sz_node);
  float* hU = (float*)alloc(sz_node);
  float* hB = (float*)alloc(sz_node);
  float* hC = (float*)alloc(sz_node);
  unsigned* agg_u = (unsigned*)alloc(sz_node);
  float* score = (float*)alloc(sz_score);
  unsigned* smax_u = (unsigned*)alloc(sz_n8);
  float* denom = (float*)alloc(sz_n8);
  float* misc = (float*)alloc(sz_misc);
  float* stat = misc;
  float* bias2 = misc + 1024;
  float* moy = misc + 1152;
  float* cnt = misc + 2176;

  const int gN = (N + 127) / 128;  // node-gemm tiles
  // embeddings
  k_node_embed<<<2048, 128, 0, stream>>>(h_in, emb_n_w, emb_n_b, h0, N);
  k_edge_embed<<<4096, 128, 0, stream>>>(e_in, emb_e_w, emb_e_b, e0u, E);

  for (int l = 0; l < 3; ++l) {
    const float* Ul = Us + (size_t)l * DF * DF;
    const float* Vl = Vs + (size_t)l * DF * DF;
    const float* Al = As + (size_t)l * DF * DF;
    const float* Bl = Bs + (size_t)l * DF * DF;
    const float* Cl = Cs + (size_t)l * DF * DF;
    k_gemm_mfma<<<gN, 512, 0, stream>>>(h0, Vl, nullptr, hV, N);
    k_gemm_mfma<<<gN, 512, 0, stream>>>(h0, Ul, nullptr, hU, N);
    k_gemm_mfma<<<gN, 512, 0, stream>>>(h0, Bl, nullptr, hB, N);
    k_gemm_mfma<<<gN, 512, 0, stream>>>(h0, Cl, nullptr, hC, N);
    k_fill_u32<<<4096, 256, 0, stream>>>(agg_u, ENC_NEGINF, (long long)N * DF);
    k_fill_u32<<<4, 256, 0, stream>>>((unsigned*)stat, 0u, 1024);
    k_edge_max<<<4096, 256, 0, stream>>>(hV, e0u, src, dst, agg_u, (long long)E * DF);
    k_node_pre_bn<<<512, 128, 0, stream>>>(hU, agg_u, stat, N);
    k_edge_mfma<0><<<512, 512, 0, stream>>>(e0u, Al, hB, hC, src, dst, stat, E);
    k_bn_finalize<<<1, 256, 0, stream>>>(stat, (float)N, (float)E);
    k_node_update<<<2048, 256, 0, stream>>>(h0, hU, stat, (long long)N * DF);
    k_edge_mfma<1><<<512, 512, 0, stream>>>(e0u, Al, hB, hC, src, dst, stat, E);
  }

  // GATv2
  k_gemm_mfma<<<gN, 512, 0, stream>>>(h0, gat_src_w, gat_src_b, hV, N);  // fs
  k_gemm_mfma<<<gN, 512, 0, stream>>>(h0, gat_dst_w, gat_dst_b, hB, N);  // fd
  float* rst = (float*)agg_u;
  k_fill_u32<<<256, 256, 0, stream>>>(smax_u, ENC_NEGINF, (long long)N * 8);
  k_fill_u32<<<256, 256, 0, stream>>>((unsigned*)denom, 0u, (long long)N * 8);
  k_fill_u32<<<4096, 256, 0, stream>>>((unsigned*)rst, 0u, (long long)N * DF);
  k_fill_u32<<<2, 256, 0, stream>>>((unsigned*)moy, 0u, 1032);
  k_gat_score<<<4096, 256, 0, stream>>>(hV, hB, src, dst, gat_attn, score, smax_u,
                                        (long long)E * 8);
  k_gat_p<<<4096, 256, 0, stream>>>(score, smax_u, dst, denom, (long long)E * 8);
  k_gat_rst<<<4096, 256, 0, stream>>>(score, denom, hV, src, dst, rst, (long long)E * DF);
  k_bias2<<<1, 128, 0, stream>>>(gat_bias, O_w, O_b, bias2);
  k_gemm_mfma<<<gN, 512, 0, stream>>>(rst, O_w, bias2, hU, N);  // h2

  // readout
  k_moy<<<128, 128, 0, stream>>>(hU, node_graph, moy, cnt, N);
  k_moy_div<<<8, 128, 0, stream>>>(moy, cnt);
  k_final_mfma<<<1024, 512, 0, stream>>>(hU, moy, src, dst, edge_graph, W1_w, W1_b,
                                         W2_w, W2_b, out, E);
}

// Round 4
// 2289.193 us; speedup vs baseline: 2.6771x; 1.0777x over previous
//
#include <hip/hip_runtime.h>

#define DF 128

typedef __attribute__((ext_vector_type(8))) short bf16x8;
typedef __attribute__((ext_vector_type(4))) float f32x4;

constexpr unsigned ENC_NEGINF = 0x007FFFFFu;  // enc(-inf)

__device__ __forceinline__ unsigned enc_f(float f) {
  unsigned u = __float_as_uint(f);
  return (u & 0x80000000u) ? ~u : (u | 0x80000000u);
}
__device__ __forceinline__ float dec_f(unsigned k) {
  unsigned u = (k & 0x80000000u) ? (k & 0x7FFFFFFFu) : ~k;
  return __uint_as_float(u);
}
__device__ __forceinline__ float sigm(float x) { return 1.f / (1.f + __expf(-x)); }
__device__ __forceinline__ unsigned short f2bf(float f) {  // RNE f32->bf16
  unsigned u = __float_as_uint(f);
  u += 0x7FFFu + ((u >> 16) & 1u);
  return (unsigned short)(u >> 16);
}
__device__ __forceinline__ float bf2f(unsigned short u) {
  return __uint_as_float(((unsigned)u) << 16);
}

// load 8 consecutive f32 (32B-aligned) -> bf16x8
__device__ __forceinline__ bf16x8 cvt8(const float* __restrict__ p) {
  float4 a = *(const float4*)p;
  float4 b = *(const float4*)(p + 4);
  bf16x8 r;
  r[0] = (short)f2bf(a.x); r[1] = (short)f2bf(a.y);
  r[2] = (short)f2bf(a.z); r[3] = (short)f2bf(a.w);
  r[4] = (short)f2bf(b.x); r[5] = (short)f2bf(b.y);
  r[6] = (short)f2bf(b.z); r[7] = (short)f2bf(b.w);
  return r;
}

// ---------------- generic fill ----------------
__global__ void k_fill_u32(unsigned* __restrict__ p, unsigned v, long long n) {
  long long i = (long long)blockIdx.x * blockDim.x + threadIdx.x;
  long long st = (long long)gridDim.x * blockDim.x;
  for (; i < n; i += st) p[i] = v;
}

// ---------------- embeddings ----------------
__global__ __launch_bounds__(128) void k_node_embed(
    const float* __restrict__ hin, const float* __restrict__ w,
    const float* __restrict__ b, float* __restrict__ h0, int rows) {
  __shared__ float Wt[64 * DF];
  __shared__ float ar[4][64];
  int tid = threadIdx.x;
  for (int i = tid; i < 64 * DF; i += 128) Wt[(i & 63) * DF + (i >> 6)] = w[i];
  float bb = b[tid];
  __syncthreads();
  for (int r0 = blockIdx.x * 4; r0 < rows; r0 += gridDim.x * 4) {
    for (int i = tid; i < 256; i += 128) ar[i >> 6][i & 63] = hin[(size_t)r0 * 64 + i];
    __syncthreads();
    float a0 = bb, a1 = bb, a2 = bb, a3 = bb;
#pragma unroll 8
    for (int k = 0; k < 64; ++k) {
      float wv = Wt[k * DF + tid];
      a0 = fmaf(ar[0][k], wv, a0); a1 = fmaf(ar[1][k], wv, a1);
      a2 = fmaf(ar[2][k], wv, a2); a3 = fmaf(ar[3][k], wv, a3);
    }
    h0[(size_t)r0 * DF + tid] = a0;
    h0[(size_t)(r0 + 1) * DF + tid] = a1;
    h0[(size_t)(r0 + 2) * DF + tid] = a2;
    h0[(size_t)(r0 + 3) * DF + tid] = a3;
    __syncthreads();
  }
}

__global__ __launch_bounds__(128) void k_edge_embed(
    const float* __restrict__ ein, const float* __restrict__ w,
    const float* __restrict__ b, unsigned short* __restrict__ e0u, int rows) {
  __shared__ float Wt[16 * DF];
  __shared__ float ar[4][16];
  int tid = threadIdx.x;
  for (int i = tid; i < 16 * DF; i += 128) Wt[(i & 15) * DF + (i >> 4)] = w[i];
  float bb = b[tid];
  __syncthreads();
  for (int r0 = blockIdx.x * 4; r0 < rows; r0 += gridDim.x * 4) {
    if (tid < 64) ar[tid >> 4][tid & 15] = ein[(size_t)r0 * 16 + tid];
    __syncthreads();
    float a0 = bb, a1 = bb, a2 = bb, a3 = bb;
#pragma unroll
    for (int k = 0; k < 16; ++k) {
      float wv = Wt[k * DF + tid];
      a0 = fmaf(ar[0][k], wv, a0); a1 = fmaf(ar[1][k], wv, a1);
      a2 = fmaf(ar[2][k], wv, a2); a3 = fmaf(ar[3][k], wv, a3);
    }
    e0u[(size_t)r0 * DF + tid] = f2bf(a0);
    e0u[(size_t)(r0 + 1) * DF + tid] = f2bf(a1);
    e0u[(size_t)(r0 + 2) * DF + tid] = f2bf(a2);
    e0u[(size_t)(r0 + 3) * DF + tid] = f2bf(a3);
    __syncthreads();
  }
}

// ---------------- MFMA [rows,128] @ W[128,128]^T (+bias) ----------------
// 8 waves/block, 128-row tiles, 16 rows/wave. OUTBF: write bf16 else f32.
// Wb LDS layout: slot s=(ct*4+ks)*64+lane holds W[ct*16+(lane&15)][ks*32+(lane>>4)*8 ..+8]
template <int OUTBF>
__global__ __launch_bounds__(512) void k_gemm_mfma(
    const float* __restrict__ A, const float* __restrict__ W,
    const float* __restrict__ bias, void* __restrict__ outv, int rows) {
  __shared__ short Wb[2048 * 8];  // 32 KB
  int tid = threadIdx.x;
  for (int s = tid; s < 2048; s += 512) {
    int ct = s >> 8, ks = (s >> 6) & 3, l = s & 63;
    int row = ct * 16 + (l & 15), k0 = ks * 32 + (l >> 4) * 8;
    *(bf16x8*)&Wb[s * 8] = cvt8(W + (size_t)row * DF + k0);
  }
  __syncthreads();
  float* outf = (float*)outv;
  unsigned short* outb = (unsigned short*)outv;
  int wid = tid >> 6, lane = tid & 63, q = lane >> 4, m = lane & 15;
  int ntiles = (rows + 127) >> 7;
  for (int t = blockIdx.x; t < ntiles; t += gridDim.x) {
    int r0 = t * 128 + wid * 16;
    int rr = r0 + m;
    if (rr >= rows) rr = rows - 1;
    const float* ap = A + (size_t)rr * DF + q * 8;
    bf16x8 a[4];
#pragma unroll
    for (int ks = 0; ks < 4; ++ks) a[ks] = cvt8(ap + 32 * ks);
#pragma unroll
    for (int ct = 0; ct < 8; ++ct) {
      f32x4 acc = {0.f, 0.f, 0.f, 0.f};
#pragma unroll
      for (int ks = 0; ks < 4; ++ks) {
        bf16x8 b = *(const bf16x8*)&Wb[((ct * 4 + ks) * 64 + lane) * 8];
        acc = __builtin_amdgcn_mfma_f32_16x16x32_bf16(a[ks], b, acc, 0, 0, 0);
      }
      int col = ct * 16 + m;
      float bb = bias ? bias[col] : 0.f;
#pragma unroll
      for (int j = 0; j < 4; ++j) {
        int row = r0 + q * 4 + j;
        if (row < rows) {
          if (OUTBF) outb[(size_t)row * DF + col] = f2bf(acc[j] + bb);
          else outf[(size_t)row * DF + col] = acc[j] + bb;
        }
      }
    }
  }
}

// ---------------- MFMA edge pass: x = e@As^T + hB[dst] + hC[src] ----------------
// APPLY=0: accumulate column sum/sumsq into stat[512..768).
// APPLY=1: e0u += relu((x - mean)*inv), bf16.
template <int APPLY>
__global__ __launch_bounds__(512) void k_edge_mfma(
    unsigned short* __restrict__ e0u, const float* __restrict__ As,
    const unsigned short* __restrict__ hBb, const unsigned short* __restrict__ hCb,
    const int* __restrict__ src, const int* __restrict__ dst,
    float* __restrict__ stat, int E) {
  __shared__ short Wb[2048 * 8];     // 32 KB
  __shared__ float xt[8][16 * 132];  // per-wave 16x128 f32 tile, pad 4
  int tid = threadIdx.x;
  for (int s = tid; s < 2048; s += 512) {
    int ct = s >> 8, ks = (s >> 6) & 3, l = s & 63;
    int row = ct * 16 + (l & 15), k0 = ks * 32 + (l >> 4) * 8;
    *(bf16x8*)&Wb[s * 8] = cvt8(As + (size_t)row * DF + k0);
  }
  int wid = tid >> 6, lane = tid & 63, q = lane >> 4, m = lane & 15;
  float* xw = xt[wid];
  float ps0 = 0.f, ps1 = 0.f, pq0 = 0.f, pq1 = 0.f;
  __syncthreads();
  int ntiles = (E + 127) >> 7;
  for (int t = blockIdx.x; t < ntiles; t += gridDim.x) {
    int r0 = t * 128 + wid * 16;
    int edge = r0 + m;
    bool ok = edge < E;
    int ec = ok ? edge : E - 1;
    const unsigned short* ep = e0u + (size_t)ec * DF + q * 8;
    bf16x8 a[4];
#pragma unroll
    for (int ks = 0; ks < 4; ++ks) a[ks] = *(const bf16x8*)(ep + 32 * ks);
#pragma unroll
    for (int ct = 0; ct < 8; ++ct) {
      f32x4 acc = {0.f, 0.f, 0.f, 0.f};
#pragma unroll
      for (int ks = 0; ks < 4; ++ks) {
        bf16x8 b = *(const bf16x8*)&Wb[((ct * 4 + ks) * 64 + lane) * 8];
        acc = __builtin_amdgcn_mfma_f32_16x16x32_bf16(a[ks], b, acc, 0, 0, 0);
      }
#pragma unroll
      for (int j = 0; j < 4; ++j) xw[(q * 4 + j) * 132 + ct * 16 + m] = acc[j];
    }
    __syncthreads();
    // row-layout phase: lane handles row m, cols q*8+32ks..+8
    int sidx = src[ec], didx = dst[ec];
    const unsigned short* pb = hBb + (size_t)didx * DF;
    const unsigned short* pc = hCb + (size_t)sidx * DF;
#pragma unroll
    for (int ks = 0; ks < 4; ++ks) {
      int c0 = q * 8 + 32 * ks;
      float* xp = &xw[m * 132 + c0];
      bf16x8 gb = *(const bf16x8*)(pb + c0);
      bf16x8 gc = *(const bf16x8*)(pc + c0);
      float x[8];
#pragma unroll
      for (int i = 0; i < 8; ++i)
        x[i] = xp[i] + bf2f((unsigned short)gb[i]) + bf2f((unsigned short)gc[i]);
      if (APPLY) {
        bf16x8 nv;
#pragma unroll
        for (int i = 0; i < 8; ++i) {
          float mm = stat[768 + c0 + i], iv = stat[896 + c0 + i];
          nv[i] = (short)f2bf(bf2f((unsigned short)a[ks][i]) + fmaxf((x[i] - mm) * iv, 0.f));
        }
        if (ok) *(bf16x8*)(e0u + (size_t)ec * DF + c0) = nv;
      } else {
#pragma unroll
        for (int i = 0; i < 8; ++i) xp[i] = ok ? x[i] : 0.f;
      }
    }
    if (!APPLY) {
      __syncthreads();
      // column stats: lane handles cols 2*lane, 2*lane+1 of this wave's tile
#pragma unroll 4
      for (int r = 0; r < 16; ++r) {
        float2 v = *(float2*)&xw[r * 132 + 2 * lane];
        ps0 += v.x; ps1 += v.y;
        pq0 += v.x * v.x; pq1 += v.y * v.y;
      }
    }
    __syncthreads();
  }
  if (!APPLY) {
    atomicAdd(&stat[512 + 2 * lane], ps0);
    atomicAdd(&stat[512 + 2 * lane + 1], ps1);
    atomicAdd(&stat[640 + 2 * lane], pq0);
    atomicAdd(&stat[640 + 2 * lane + 1], pq1);
  }
}

// ---------------- layer: m = hV[src]*sigmoid(e); segment_max -> agg ----------------
__global__ __launch_bounds__(256) void k_edge_max(
    const unsigned short* __restrict__ hVb, const unsigned short* __restrict__ e0u,
    const int* __restrict__ src, const int* __restrict__ dst,
    unsigned* __restrict__ agg_u, long long total) {
  long long i = (long long)blockIdx.x * blockDim.x + threadIdx.x;
  long long st = (long long)gridDim.x * blockDim.x;
  for (; i < total; i += st) {
    int e = (int)(i >> 7), d = (int)(i & 127);
    float m = bf2f(hVb[(size_t)src[e] * DF + d]) * sigm(bf2f(e0u[i]));
    atomicMax(&agg_u[(size_t)dst[e] * DF + d], enc_f(m));
  }
}

// tmp_h = hU + decode(agg); accumulate node BN stats
__global__ __launch_bounds__(128) void k_node_pre_bn(
    float* __restrict__ hU, const unsigned* __restrict__ agg_u,
    float* __restrict__ stat, int rows) {
  int tid = threadIdx.x;
  float ps = 0.f, pq = 0.f;
  for (int n = blockIdx.x; n < rows; n += gridDim.x) {
    size_t idx = (size_t)n * DF + tid;
    unsigned k = agg_u[idx];
    float a = (k == ENC_NEGINF) ? 0.f : dec_f(k);
    float t = hU[idx] + a;
    hU[idx] = t;
    ps += t; pq += t * t;
  }
  atomicAdd(&stat[tid], ps);
  atomicAdd(&stat[128 + tid], pq);
}

// finalize BN stats
__global__ void k_bn_finalize(float* __restrict__ stat, float nN, float nE) {
  int tid = threadIdx.x;
  if (tid < 128) {
    float mean = stat[tid] / nN;
    float var = stat[128 + tid] / nN - mean * mean;
    stat[256 + tid] = mean;
    stat[384 + tid] = rsqrtf(fmaxf(var, 0.f) + 1e-5f);
  } else {
    int d = tid - 128;
    float mean = stat[512 + d] / nE;
    float var = stat[640 + d] / nE - mean * mean;
    stat[768 + d] = mean;
    stat[896 + d] = rsqrtf(fmaxf(var, 0.f) + 1e-5f);
  }
}

__global__ __launch_bounds__(256) void k_node_update(
    float* __restrict__ h0, const float* __restrict__ hU,
    const float* __restrict__ stat, long long total) {
  long long i = (long long)blockIdx.x * blockDim.x + threadIdx.x;
  long long st = (long long)gridDim.x * blockDim.x;
  for (; i < total; i += st) {
    int d = (int)(i & 127);
    float t = (hU[i] - stat[256 + d]) * stat[384 + d];
    h0[i] += fmaxf(t, 0.f);
  }
}

// ---------------- GATv2 ----------------
__global__ __launch_bounds__(256) void k_gat_score(
    const unsigned short* __restrict__ fsb, const unsigned short* __restrict__ fdb,
    const int* __restrict__ src, const int* __restrict__ dst,
    const float* __restrict__ attn, float* __restrict__ score,
    unsigned* __restrict__ smax_u, long long total) {
  long long i = (long long)blockIdx.x * blockDim.x + threadIdx.x;
  long long st = (long long)gridDim.x * blockDim.x;
  for (; i < total; i += st) {
    int e = (int)(i >> 3), m = (int)(i & 7);
    int s = src[e], dn = dst[e];
    const unsigned short* ps = fsb + (size_t)s * DF + m * 16;
    const unsigned short* pd = fdb + (size_t)dn * DF + m * 16;
    const float* pa = attn + m * 16;
    bf16x8 s0 = *(const bf16x8*)ps;
    bf16x8 s1 = *(const bf16x8*)(ps + 8);
    bf16x8 d0 = *(const bf16x8*)pd;
    bf16x8 d1 = *(const bf16x8*)(pd + 8);
    float acc = 0.f;
#pragma unroll
    for (int k = 0; k < 8; ++k) {
      float z = bf2f((unsigned short)s0[k]) + bf2f((unsigned short)d0[k]);
      z = (z > 0.f) ? z : 0.2f * z;
      acc = fmaf(z, pa[k], acc);
      float z2 = bf2f((unsigned short)s1[k]) + bf2f((unsigned short)d1[k]);
      z2 = (z2 > 0.f) ? z2 : 0.2f * z2;
      acc = fmaf(z2, pa[k + 8], acc);
    }
    score[i] = acc;
    atomicMax(&smax_u[(size_t)dn * 8 + m], enc_f(acc));
  }
}

__global__ __launch_bounds__(256) void k_gat_p(
    float* __restrict__ score, const unsigned* __restrict__ smax_u,
    const int* __restrict__ dst, float* __restrict__ denom, long long total) {
  long long i = (long long)blockIdx.x * blockDim.x + threadIdx.x;
  long long st = (long long)gridDim.x * blockDim.x;
  for (; i < total; i += st) {
    int e = (int)(i >> 3), m = (int)(i & 7);
    int dn = dst[e];
    float p = __expf(score[i] - dec_f(smax_u[(size_t)dn * 8 + m]));
    score[i] = p;
    atomicAdd(&denom[(size_t)dn * 8 + m], p);
  }
}

__global__ __launch_bounds__(256) void k_gat_rst(
    const float* __restrict__ score, const float* __restrict__ denom,
    const unsigned short* __restrict__ fsb, const int* __restrict__ src,
    const int* __restrict__ dst, float* __restrict__ rst, long long total) {
  long long i = (long long)blockIdx.x * blockDim.x + threadIdx.x;
  long long st = (long long)gridDim.x * blockDim.x;
  for (; i < total; i += st) {
    int e = (int)(i >> 7), d = (int)(i & 127), m = d >> 4;
    int s = src[e], dn = dst[e];
    float a = score[(size_t)e * 8 + m] / denom[(size_t)dn * 8 + m];
    atomicAdd(&rst[(size_t)dn * DF + d], a * bf2f(fsb[(size_t)s * DF + d]));
  }
}

// bias2 = O_b + gat_bias @ O_w^T
__global__ void k_bias2(const float* __restrict__ gat_bias,
                        const float* __restrict__ O_w,
                        const float* __restrict__ O_b, float* __restrict__ bias2) {
  int d = threadIdx.x;
  float acc = O_b[d];
  for (int k = 0; k < DF; ++k) acc = fmaf(gat_bias[k], O_w[(size_t)d * DF + k], acc);
  bias2[d] = acc;
}

// ---------------- readout ----------------
__global__ __launch_bounds__(128) void k_moy(
    const unsigned short* __restrict__ h2b, const int* __restrict__ ng,
    float* __restrict__ moy, float* __restrict__ cnt, int rows) {
  int tid = threadIdx.x;
  int per = (rows + gridDim.x - 1) / gridDim.x;
  int n0 = blockIdx.x * per;
  int n1 = min(rows, n0 + per);
  if (n0 >= n1) return;
  int cur = ng[n0];
  float acc = 0.f; int c = 0;
  for (int n = n0; n < n1; ++n) {
    int g = ng[n];
    if (g != cur) {
      atomicAdd(&moy[cur * DF + tid], acc);
      if (tid == 0) atomicAdd(&cnt[cur], (float)c);
      acc = 0.f; c = 0; cur = g;
    }
    acc += bf2f(h2b[(size_t)n * DF + tid]);
    ++c;
  }
  atomicAdd(&moy[cur * DF + tid], acc);
  if (tid == 0) atomicAdd(&cnt[cur], (float)c);
}

__global__ void k_moy_div(const float* __restrict__ moy, const float* __restrict__ cnt,
                          unsigned short* __restrict__ moyb) {
  int i = blockIdx.x * DF + threadIdx.x;
  moyb[i] = f2bf(moy[i] / cnt[blockIdx.x]);
}

// ---------------- fused MFMA head ----------------
// y = relu([moy|h_src|h_dst] @ W1^T + b1); out = sigmoid(y.W2 + b2)
// Wb slot s=(ct*12+ks)*64+lane holds W1[ct*16+(lane&15)][ks*32+(lane>>4)*8 ..+8]
__global__ __launch_bounds__(512) void k_final_mfma(
    const unsigned short* __restrict__ h2b, const unsigned short* __restrict__ moyb,
    const int* __restrict__ src, const int* __restrict__ dst,
    const int* __restrict__ eg, const float* __restrict__ W1,
    const float* __restrict__ W1b, const float* __restrict__ W2,
    const float* __restrict__ W2b, float* __restrict__ out, int E) {
  __shared__ short Wb[6144 * 8];  // 96 KB
  int tid = threadIdx.x;
  for (int s = tid; s < 6144; s += 512) {
    int ct = s / 768, ks = (s >> 6) % 12, l = s & 63;
    int row = ct * 16 + (l & 15), k0 = ks * 32 + (l >> 4) * 8;
    *(bf16x8*)&Wb[s * 8] = cvt8(W1 + (size_t)row * 384 + k0);
  }
  __syncthreads();
  int wid = tid >> 6, lane = tid & 63, q = lane >> 4, m = lane & 15;
  float w2b = W2b[0];
  int ntiles = (E + 127) >> 7;
  for (int t = blockIdx.x; t < ntiles; t += gridDim.x) {
    int r0 = t * 128 + wid * 16;
    int edge = r0 + m;
    if (edge >= E) edge = E - 1;
    int g = eg[edge], s = src[edge], d = dst[edge];
    const unsigned short* b0 = moyb + (size_t)g * DF;
    const unsigned short* b1p = h2b + (size_t)s * DF;
    const unsigned short* b2p = h2b + (size_t)d * DF;
    bf16x8 a[12];
#pragma unroll
    for (int ks = 0; ks < 12; ++ks) {
      int k = ks * 32 + q * 8;
      const unsigned short* p =
          (k < 128) ? (b0 + k) : ((k < 256) ? (b1p + k - 128) : (b2p + k - 256));
      a[ks] = *(const bf16x8*)p;
    }
    float v0 = 0.f, v1 = 0.f, v2 = 0.f, v3 = 0.f;
#pragma unroll
    for (int ct = 0; ct < 8; ++ct) {
      f32x4 acc = {0.f, 0.f, 0.f, 0.f};
#pragma unroll
      for (int ks = 0; ks < 12; ++ks) {
        bf16x8 b = *(const bf16x8*)&Wb[((ct * 12 + ks) * 64 + lane) * 8];
        acc = __builtin_amdgcn_mfma_f32_16x16x32_bf16(a[ks], b, acc, 0, 0, 0);
      }
      int col = ct * 16 + m;
      float bb = W1b[col], ww = W2[col];
      v0 += fmaxf(acc[0] + bb, 0.f) * ww;
      v1 += fmaxf(acc[1] + bb, 0.f) * ww;
      v2 += fmaxf(acc[2] + bb, 0.f) * ww;
      v3 += fmaxf(acc[3] + bb, 0.f) * ww;
    }
#pragma unroll
    for (int mask = 1; mask <= 8; mask <<= 1) {
      v0 += __shfl_xor(v0, mask, 64);
      v1 += __shfl_xor(v1, mask, 64);
      v2 += __shfl_xor(v2, mask, 64);
      v3 += __shfl_xor(v3, mask, 64);
    }
    if (m == 0) {
      int rb = r0 + q * 4;
      if (rb < E) out[rb] = sigm(v0 + w2b);
      if (rb + 1 < E) out[rb + 1] = sigm(v1 + w2b);
      if (rb + 2 < E) out[rb + 2] = sigm(v2 + w2b);
      if (rb + 3 < E) out[rb + 3] = sigm(v3 + w2b);
    }
  }
}

extern "C" void kernel_launch(void* const* d_in, const int* in_sizes, int n_in,
                              void* d_out, int out_size, void* d_ws, size_t ws_size,
                              hipStream_t stream) {
  const float* h_in = (const float*)d_in[0];
  const float* e_in = (const float*)d_in[1];
  const int* src = (const int*)d_in[2];
  const int* dst = (const int*)d_in[3];
  const int* node_graph = (const int*)d_in[4];
  const int* edge_graph = (const int*)d_in[5];
  const float* emb_n_w = (const float*)d_in[6];
  const float* emb_n_b = (const float*)d_in[7];
  const float* emb_e_w = (const float*)d_in[8];
  const float* emb_e_b = (const float*)d_in[9];
  const float* Us = (const float*)d_in[10];
  const float* Vs = (const float*)d_in[11];
  const float* As = (const float*)d_in[12];
  const float* Bs = (const float*)d_in[13];
  const float* Cs = (const float*)d_in[14];
  const float* gat_src_w = (const float*)d_in[15];
  const float* gat_src_b = (const float*)d_in[16];
  const float* gat_dst_w = (const float*)d_in[17];
  const float* gat_dst_b = (const float*)d_in[18];
  const float* gat_attn = (const float*)d_in[19];
  const float* gat_bias = (const float*)d_in[20];
  const float* O_w = (const float*)d_in[21];
  const float* O_b = (const float*)d_in[22];
  const float* W1_w = (const float*)d_in[23];
  const float* W1_b = (const float*)d_in[24];
  const float* W2_w = (const float*)d_in[25];
  const float* W2_b = (const float*)d_in[26];
  float* out = (float*)d_out;

  const int N = in_sizes[0] / 64;   // 30000
  const int E = in_sizes[1] / 16;   // 360000

  const size_t sz_e0 = (size_t)E * DF * sizeof(unsigned short);
  const size_t sz_node = (size_t)N * DF * sizeof(float);
  const size_t sz_nodeb = (size_t)N * DF * sizeof(unsigned short);
  const size_t sz_score = (size_t)E * 8 * sizeof(float);
  const size_t sz_n8 = (size_t)N * 8 * sizeof(float);
  const size_t sz_misc = 4096 * sizeof(float);
  const size_t needed =
      sz_e0 + 3 * sz_node + 4 * sz_nodeb + sz_score + 2 * sz_n8 + sz_misc;
  if (ws_size < needed) {
    k_fill_u32<<<256, 256, 0, stream>>>((unsigned*)out, 0xBF800000u, (long long)out_size);
    return;
  }

  char* wp = (char*)d_ws;
  auto alloc = [&](size_t bytes) { void* p = wp; wp += bytes; return p; };
  unsigned short* e0u = (unsigned short*)alloc(sz_e0);
  float* h0 = (float*)alloc(sz_node);
  float* hU = (float*)alloc(sz_node);
  unsigned* agg_u = (unsigned*)alloc(sz_node);  // also rst (f32)
  unsigned short* hVb = (unsigned short*)alloc(sz_nodeb);
  unsigned short* hBb = (unsigned short*)alloc(sz_nodeb);
  unsigned short* hCb = (unsigned short*)alloc(sz_nodeb);
  unsigned short* h2b = (unsigned short*)alloc(sz_nodeb);
  float* score = (float*)alloc(sz_score);
  unsigned* smax_u = (unsigned*)alloc(sz_n8);
  float* denom = (float*)alloc(sz_n8);
  float* misc = (float*)alloc(sz_misc);
  float* stat = misc;                                   // [0,1024)
  float* bias2 = misc + 1024;                           // [1024,1152)
  float* moy = misc + 1152;                             // [1152,2176)
  float* cnt = misc + 2176;                             // [2176,2184)
  unsigned short* moyb = (unsigned short*)(misc + 2304);  // 1024 bf16

  const int gN = (N + 127) / 128;
  // embeddings
  k_node_embed<<<2048, 128, 0, stream>>>(h_in, emb_n_w, emb_n_b, h0, N);
  k_edge_embed<<<4096, 128, 0, stream>>>(e_in, emb_e_w, emb_e_b, e0u, E);

  for (int l = 0; l < 3; ++l) {
    const float* Ul = Us + (size_t)l * DF * DF;
    const float* Vl = Vs + (size_t)l * DF * DF;
    const float* Al = As + (size_t)l * DF * DF;
    const float* Bl = Bs + (size_t)l * DF * DF;
    const float* Cl = Cs + (size_t)l * DF * DF;
    k_gemm_mfma<1><<<gN, 512, 0, stream>>>(h0, Vl, nullptr, hVb, N);
    k_gemm_mfma<0><<<gN, 512, 0, stream>>>(h0, Ul, nullptr, hU, N);
    k_gemm_mfma<1><<<gN, 512, 0, stream>>>(h0, Bl, nullptr, hBb, N);
    k_gemm_mfma<1><<<gN, 512, 0, stream>>>(h0, Cl, nullptr, hCb, N);
    k_fill_u32<<<4096, 256, 0, stream>>>(agg_u, ENC_NEGINF, (long long)N * DF);
    k_fill_u32<<<4, 256, 0, stream>>>((unsigned*)stat, 0u, 1024);
    k_edge_max<<<4096, 256, 0, stream>>>(hVb, e0u, src, dst, agg_u, (long long)E * DF);
    k_node_pre_bn<<<512, 128, 0, stream>>>(hU, agg_u, stat, N);
    k_edge_mfma<0><<<512, 512, 0, stream>>>(e0u, Al, hBb, hCb, src, dst, stat, E);
    k_bn_finalize<<<1, 256, 0, stream>>>(stat, (float)N, (float)E);
    k_node_update<<<2048, 256, 0, stream>>>(h0, hU, stat, (long long)N * DF);
    k_edge_mfma<1><<<512, 512, 0, stream>>>(e0u, Al, hBb, hCb, src, dst, stat, E);
  }

  // GATv2: fs -> hVb, fd -> hBb
  k_gemm_mfma<1><<<gN, 512, 0, stream>>>(h0, gat_src_w, gat_src_b, hVb, N);
  k_gemm_mfma<1><<<gN, 512, 0, stream>>>(h0, gat_dst_w, gat_dst_b, hBb, N);
  float* rst = (float*)agg_u;
  k_fill_u32<<<256, 256, 0, stream>>>(smax_u, ENC_NEGINF, (long long)N * 8);
  k_fill_u32<<<256, 256, 0, stream>>>((unsigned*)denom, 0u, (long long)N * 8);
  k_fill_u32<<<4096, 256, 0, stream>>>((unsigned*)rst, 0u, (long long)N * DF);
  k_fill_u32<<<2, 256, 0, stream>>>((unsigned*)moy, 0u, 1032);
  k_gat_score<<<4096, 256, 0, stream>>>(hVb, hBb, src, dst, gat_attn, score, smax_u,
                                        (long long)E * 8);
  k_gat_p<<<4096, 256, 0, stream>>>(score, smax_u, dst, denom, (long long)E * 8);
  k_gat_rst<<<4096, 256, 0, stream>>>(score, denom, hVb, src, dst, rst, (long long)E * DF);
  k_bias2<<<1, 128, 0, stream>>>(gat_bias, O_w, O_b, bias2);
  k_gemm_mfma<1><<<gN, 512, 0, stream>>>(rst, O_w, bias2, h2b, N);  // h2

  // readout
  k_moy<<<128, 128, 0, stream>>>(h2b, node_graph, moy, cnt, N);
  k_moy_div<<<8, 128, 0, stream>>>(moy, cnt, moyb);
  k_final_mfma<<<1024, 512, 0, stream>>>(h2b, moyb, src, dst, edge_graph, W1_w, W1_b,
                                         W2_w, W2_b, out, E);
}